// Round 3
// baseline (402.865 us; speedup 1.0000x reference)
//
#include <hip/hip_runtime.h>
#include <hip/hip_bf16.h>

#define TS 64
#define NB 256
#define DI 32
#define NH 10
#define IND 42

struct Cx { float r, i; };
__device__ __forceinline__ Cx cmul(Cx a, Cx b){ return { a.r*b.r - a.i*b.i, a.r*b.i + a.i*b.r }; }
__device__ __forceinline__ Cx csel(Cx a, Cx b, int bit){ return { bit ? b.r : a.r, bit ? b.i : a.i }; }

__device__ __forceinline__ float wsum(float x){
  #pragma unroll
  for (int m = 1; m < 64; m <<= 1) x += __shfl_xor(x, m);
  return x;
}

// One block per batch element b. Wave g (0..3) simulates the gate-g circuit.
// State: 1024 amps = 64 lanes x 16 slots. Wire w <-> bit w of the flat index.
// Slot bits = wires 0..3, lane bits 0..5 = wires 4..9.
__global__ __launch_bounds__(256, 1)
void qlstm_kernel(const float* __restrict__ xin,
                  const float* __restrict__ qp,
                  const float* __restrict__ Wf, const float* __restrict__ bfp,
                  const float* __restrict__ Wi, const float* __restrict__ bip,
                  const float* __restrict__ Wg, const float* __restrict__ bgp,
                  const float* __restrict__ Wo, const float* __restrict__ bop,
                  float* __restrict__ out)
{
  __shared__ float lx[TS][DI];                    // this block's x[t,:] as f32
  __shared__ float lW[4][NH][IND];
  __shared__ float lB[4][NH];
  __shared__ __align__(16) float lU1[NH][8];      // layer-1 combined RY*RX*RZ (row0, row1)
  __shared__ __align__(16) float lU2[NH][8];      // layer-2 combined
  __shared__ __align__(16) float lv[4][NH][4];    // per-wave encoded+layer1 2-vectors
  __shared__ float lq[4][NH];
  __shared__ float lhx[NH];

  const int tid  = threadIdx.x;
  const int b    = blockIdx.x;
  const int g    = tid >> 6;
  const int lane = tid & 63;

  // ---------------- init: stage inputs to LDS ----------------
  for (int i = tid; i < TS*DI; i += 256) {
    int tt = i >> 5, d = i & 31;
    lx[tt][d] = xin[(size_t)tt*(NB*DI) + b*DI + d];
  }
  {
    const float* Wp[4] = { Wf, Wi, Wg, Wo };
    const float* bp[4] = { bfp, bip, bgp, bop };
    for (int gg = 0; gg < 4; gg++) {
      for (int i = tid; i < NH*IND; i += 256) (&lW[gg][0][0])[i] = Wp[gg][i];
      if (tid < NH) lB[gg][tid] = bp[gg][tid];
    }
  }
  if (tid < 20) {  // U = RY(t3)*RX(t2)*RZ(t1) per (layer, wire)
    int l = tid / 10, w = tid % 10;
    float t1 = qp[l*30 + w*3 + 0];
    float t2 = qp[l*30 + w*3 + 1];
    float t3 = qp[l*30 + w*3 + 2];
    float c1 = __cosf(0.5f*t1), s1 = __sinf(0.5f*t1);
    float c2 = __cosf(0.5f*t2), s2 = __sinf(0.5f*t2);
    float c3 = __cosf(0.5f*t3), s3 = __sinf(0.5f*t3);
    // A = RX*RZ ; RZ = diag(c1-i s1, c1+i s1); RX = [[c2,-i s2],[-i s2,c2]]
    float A00r =  c2*c1, A00i = -c2*s1;
    float A01r =  s2*s1, A01i = -s2*c1;
    float A10r = -s2*s1, A10i = -s2*c1;
    float A11r =  c2*c1, A11i =  c2*s1;
    float* dst = (l == 0) ? lU1[w] : lU2[w];
    dst[0] = c3*A00r - s3*A10r; dst[1] = c3*A00i - s3*A10i;
    dst[2] = c3*A01r - s3*A11r; dst[3] = c3*A01i - s3*A11i;
    dst[4] = s3*A00r + c3*A10r; dst[5] = s3*A00i + c3*A10i;
    dst[6] = s3*A01r + c3*A11r; dst[7] = s3*A01i + c3*A11i;
  }
  if (tid < NH) lhx[tid] = 0.f;
  __syncthreads();

  const int l0 = lane&1, l1 = (lane>>1)&1, l2 = (lane>>2)&1,
            l3 = (lane>>3)&1, l4 = (lane>>4)&1, l5 = (lane>>5)&1;
  // prefix-parity signs over lane bits 0..k  (for Z-product measurement masks)
  float sg[6];
  { int p = l0;  sg[0] = p ? -1.f : 1.f;
    p ^= l1;     sg[1] = p ? -1.f : 1.f;
    p ^= l2;     sg[2] = p ? -1.f : 1.f;
    p ^= l3;     sg[3] = p ? -1.f : 1.f;
    p ^= l4;     sg[4] = p ? -1.f : 1.f;
    p ^= l5;     sg[5] = p ? -1.f : 1.f; }

  const int hh = lane & 15;   // output row of the gate matmul
  const int qq = lane >> 4;   // k-range group

  float cstate = 0.f, hval = 0.f;

  for (int t = 0; t < TS; t++) {
    // ---- (a) angles: pre[h] = W[h,:] . [x_t, h_{t-1}] + b[h]; then v_w = U1_w.[c,s]
    float partial = 0.f;
    if (hh < NH) {
      #pragma unroll
      for (int kk = 0; kk < 11; kk++) {
        int k = qq*11 + kk;
        if (k < IND) {
          float cv = (k < DI) ? lx[t][k] : lhx[k - DI];
          partial = fmaf(lW[g][hh][k], cv, partial);
        }
      }
    }
    partial += __shfl_xor(partial, 16);
    partial += __shfl_xor(partial, 32);
    if (qq == 0 && hh < NH) {
      float pre = partial + lB[g][hh];
      float ch = __cosf(0.5f*pre), sh = __sinf(0.5f*pre);
      const float* U = lU1[hh];
      lv[g][hh][0] = U[0]*ch + U[2]*sh;
      lv[g][hh][1] = U[1]*ch + U[3]*sh;
      lv[g][hh][2] = U[4]*ch + U[6]*sh;
      lv[g][hh][3] = U[5]*ch + U[7]*sh;
    }
    __syncthreads();

    // ---- (b) fetch per-wire 2-vectors
    Cx vz[NH], vo[NH];
    #pragma unroll
    for (int w = 0; w < NH; w++) {
      float4 tv = *reinterpret_cast<const float4*>(&lv[g][w][0]);
      vz[w] = { tv.x, tv.y };  vo[w] = { tv.z, tv.w };
    }
    // ---- (c) build state = ring1( product(v) ): parity-mask factor selection
    // wire0 idx = s0^l5, wire1 = s0^s1^l5, wire2 = s1^s2, wire3 = s2^s3,
    // wire4 = s3^l0, wires5..9 = adjacent lane-bit xors
    Cx f5 = csel(vz[5], vo[5], l0^l1);
    Cx f6 = csel(vz[6], vo[6], l1^l2);
    Cx f7 = csel(vz[7], vo[7], l2^l3);
    Cx f8 = csel(vz[8], vo[8], l3^l4);
    Cx f9 = csel(vz[9], vo[9], l4^l5);
    Cx P  = cmul(cmul(f5, f6), cmul(f7, cmul(f8, f9)));
    Cx a4[2]; a4[0] = csel(vz[4], vo[4], l0); a4[1] = csel(vo[4], vz[4], l0);  // v4[t^l0]
    Cx u0s[2]; u0s[0] = csel(vz[0], vo[0], l5); u0s[1] = csel(vo[0], vz[0], l5); // v0[t^l5]
    Cx u1s[2]; u1s[0] = csel(vz[1], vo[1], l5); u1s[1] = csel(vo[1], vz[1], l5); // v1[t^l5]
    Cx A[2];  A[0] = cmul(P, a4[0]);  A[1] = cmul(P, a4[1]);
    Cx C[4];
    #pragma unroll
    for (int s1b = 0; s1b < 2; s1b++)
      #pragma unroll
      for (int s0b = 0; s0b < 2; s0b++)
        C[s1b*2+s0b] = cmul(u1s[s0b^s1b], u0s[s0b]);
    Cx AB[8];
    #pragma unroll
    for (int s3b = 0; s3b < 2; s3b++)
      #pragma unroll
      for (int s2b = 0; s2b < 2; s2b++)
        #pragma unroll
        for (int s1b = 0; s1b < 2; s1b++) {
          Cx m23 = cmul((s2b^s3b) ? vo[3] : vz[3], (s1b^s2b) ? vo[2] : vz[2]);
          AB[s3b*4+s2b*2+s1b] = cmul(A[s3b], m23);
        }
    float sre[16], simg[16];
    #pragma unroll
    for (int s = 0; s < 16; s++) {
      int s0b = s&1, s1b = (s>>1)&1, s2b = (s>>2)&1, s3b = (s>>3)&1;
      Cx amp = cmul(AB[s3b*4+s2b*2+s1b], C[s1b*2+s0b]);
      sre[s] = amp.r; simg[s] = amp.i;
    }

    // ---- (d) layer-2 single-qubit gates
    #pragma unroll
    for (int w = 0; w < 4; w++) {          // in-lane wires
      float4 u0 = *reinterpret_cast<const float4*>(&lU2[w][0]);
      float4 u1 = *reinterpret_cast<const float4*>(&lU2[w][4]);
      #pragma unroll
      for (int s = 0; s < 16; s++) {
        if (!(s & (1 << w))) {
          int s2i = s | (1 << w);
          float ar = sre[s], ai = simg[s], br = sre[s2i], bi = simg[s2i];
          sre[s]    = u0.x*ar - u0.y*ai + u0.z*br - u0.w*bi;
          simg[s]   = u0.x*ai + u0.y*ar + u0.z*bi + u0.w*br;
          sre[s2i]  = u1.x*ar - u1.y*ai + u1.z*br - u1.w*bi;
          simg[s2i] = u1.x*ai + u1.y*ar + u1.z*bi + u1.w*br;
        }
      }
    }
    for (int w = 4; w < NH; w++) {         // cross-lane wires (rolled loop)
      float4 u0 = *reinterpret_cast<const float4*>(&lU2[w][0]);
      float4 u1 = *reinterpret_cast<const float4*>(&lU2[w][4]);
      int m   = (lane >> (w-4)) & 1;
      int msk = 1 << (w-4);
      float car = m ? u1.z : u0.x;   // coef on own amp
      float cai = m ? u1.w : u0.y;
      float cbr = m ? u1.x : u0.z;   // coef on partner amp
      float cbi = m ? u1.y : u0.w;
      #pragma unroll
      for (int s = 0; s < 16; s++) {
        float pr = __shfl_xor(sre[s],  msk);
        float pi = __shfl_xor(simg[s], msk);
        float nr = car*sre[s]  - cai*simg[s] + cbr*pr - cbi*pi;
        float ni = car*simg[s] + cai*sre[s]  + cbi*pr + cbr*pi;
        sre[s] = nr; simg[s] = ni;
      }
    }

    // ---- (e) measurement: ring2 folded into Z-product masks
    float p[16];
    #pragma unroll
    for (int s = 0; s < 16; s++) p[s] = sre[s]*sre[s] + simg[s]*simg[s];
    #pragma unroll
    for (int bit = 1; bit < 16; bit <<= 1) {   // in-lane WHT
      #pragma unroll
      for (int s = 0; s < 16; s++) {
        if (!(s & bit)) {
          float aa = p[s], bb = p[s|bit];
          p[s] = aa + bb; p[s|bit] = aa - bb;
        }
      }
    }
    float E[10];
    E[0] = wsum(p[14] * sg[5]);   // <Z on wire0> = parity(wires 1..9)
    E[1] = wsum(p[3]);            // parity(wires 0..1)
    E[2] = wsum(p[7]);
    E[3] = wsum(p[15]);
    E[4] = wsum(p[15]*sg[0]);
    E[5] = wsum(p[15]*sg[1]);
    E[6] = wsum(p[15]*sg[2]);
    E[7] = wsum(p[15]*sg[3]);
    E[8] = wsum(p[15]*sg[4]);
    E[9] = wsum(p[15]*sg[5]);

    // ---- (f) nonlinearity per gate-wave
    float qv = E[0];
    #pragma unroll
    for (int h2 = 1; h2 < NH; h2++) qv = (lane == h2) ? E[h2] : qv;
    float act;
    if (g == 2) { float e = __expf(2.f*qv); act = 1.f - 2.f/(e + 1.f); }   // tanh
    else        { act = 1.f/(1.f + __expf(-qv)); }                          // sigmoid
    if (lane < NH) lq[g][lane] = act;
    __syncthreads();

    // ---- (g) LSTM cell update (all waves redundantly; wave 0 publishes)
    if (lane < NH) {
      float fv = lq[0][lane], iv = lq[1][lane], gv = lq[2][lane], ov = lq[3][lane];
      cstate = fv*cstate + iv*gv;
      float e = __expf(2.f*cstate);
      hval = ov*(1.f - 2.f/(e + 1.f));
      if (g == 0) {
        lhx[lane] = hval;
        out[(size_t)t*(NB*NH) + b*NH + lane] = hval;   // f32 output per reference dtype
      }
    }
    __syncthreads();
  }

  if (g == 0 && lane < NH) {
    out[(size_t)TS*NB*NH + b*NH + lane]          = hval;
    out[(size_t)TS*NB*NH + NB*NH + b*NH + lane]  = cstate;
  }
}

extern "C" void kernel_launch(void* const* d_in, const int* in_sizes, int n_in,
                              void* d_out, int out_size, void* d_ws, size_t ws_size,
                              hipStream_t stream) {
  (void)in_sizes; (void)n_in; (void)d_ws; (void)ws_size; (void)out_size;
  qlstm_kernel<<<dim3(NB), dim3(256), 0, stream>>>(
      (const float*)d_in[0], (const float*)d_in[1],
      (const float*)d_in[2], (const float*)d_in[3],
      (const float*)d_in[4], (const float*)d_in[5],
      (const float*)d_in[6], (const float*)d_in[7],
      (const float*)d_in[8], (const float*)d_in[9],
      (float*)d_out);
}